// Round 11
// baseline (2842.397 us; speedup 1.0000x reference)
//
#include <hip/hip_runtime.h>
#include <stdint.h>
#include <math.h>

typedef unsigned long long u64;

#define NROW 12288
#define DFEAT 512
#define HDIM  1024
#define NB    96   // NROW/128
#define LISTCAP 3072

// ==================================================================================
// NUMERICS CONTRACT (validated round 9, absmax 1.95e-3):
//   - every GEMM C element = single-accumulator FMA chain, k ascending, in panels
//     (512) for K=512 and (512,512) for K=1024, panels merged with one f32 add;
//   - norm = numpy classic pairwise (unchanged);
//   - top-32: exact byte-radix select (same selected SET as u64-key pop loop);
//     0.5v+0.5v symmetric scatter unchanged.
// Round 11: topk v3 — no LDS row copy. Pass 1 streams the row for the top-byte
// histogram; pass 2 re-reads (L2/L3-hot), emits definite winners (byte>b3),
// compacts the C<=3072 threshold-bin candidates into an LDS list, and zeroes the
// row. Radix bytes 2,1,0 then run over the tiny list. LDS 53->29KB => 5 blk/CU.
// Exact fallbacks for C>LISTCAP (global re-read refine) and <32 nonzeros.
// GEMMs/norm/scatter identical to round 10 (best measured). Chains bit-identical.
// ==================================================================================

// ---------------- MLP GEMM: 128x128 tile, 8x8/thread (2x2 groups of 4x4) ----------
template <int MODE, int NPANEL>
__global__ __launch_bounds__(256, 3) void gemm128(
    const float* __restrict__ A, const float* __restrict__ B,
    const float* __restrict__ bias, const float* __restrict__ resid,
    float* __restrict__ C, int Nn, int K)
{
  __shared__ float As[32][132];   // [k][m], XOR-swizzled m-groups
  __shared__ float Bs[32][132];   // [k][n]
  const int t = threadIdx.x;
  const int tn = t & 15, tm = t >> 4;
  const size_t m0 = (size_t)blockIdx.y * 128, n0 = (size_t)blockIdx.x * 128;

  float cur[2][2][4][4] = {};             // [ih][jh][i][j]
  float tot[2][2][4][4];                  // used only when NPANEL==2

  for (int kt = 0; kt < K; kt += 32) {
#pragma unroll
    for (int u = 0; u < 4; ++u) {
      int f = u * 256 + t;
      int r = f >> 3, c = f & 7;
      int pm = (r & 3) + 4 * ((r >> 2) ^ c);   // swizzled m-slot (bijective per k-row)
      float4 va = *(const float4*)(A + (m0 + r) * (size_t)K + kt + 4 * c);
      As[4 * c + 0][pm] = va.x; As[4 * c + 1][pm] = va.y;
      As[4 * c + 2][pm] = va.z; As[4 * c + 3][pm] = va.w;
      float4 vb = *(const float4*)(B + (n0 + r) * (size_t)K + kt + 4 * c);
      Bs[4 * c + 0][pm] = vb.x; Bs[4 * c + 1][pm] = vb.y;
      Bs[4 * c + 2][pm] = vb.z; Bs[4 * c + 3][pm] = vb.w;
    }
    __syncthreads();
#pragma unroll 4
    for (int kk = 0; kk < 32; ++kk) {
      const int key = kk >> 2;
      float4 a0 = *(const float4*)&As[kk][4 * (tm ^ key)];
      float4 a1 = *(const float4*)&As[kk][4 * (16 + (tm ^ key))];
      float4 b0 = *(const float4*)&Bs[kk][4 * (tn ^ key)];
      float4 b1 = *(const float4*)&Bs[kk][4 * (16 + (tn ^ key))];
      float av[2][4] = {{a0.x, a0.y, a0.z, a0.w}, {a1.x, a1.y, a1.z, a1.w}};
      float bv[2][4] = {{b0.x, b0.y, b0.z, b0.w}, {b1.x, b1.y, b1.z, b1.w}};
#pragma unroll
      for (int ih = 0; ih < 2; ++ih)
#pragma unroll
        for (int jh = 0; jh < 2; ++jh)
#pragma unroll
          for (int i = 0; i < 4; ++i)
#pragma unroll
            for (int j = 0; j < 4; ++j)
              cur[ih][jh][i][j] = fmaf(av[ih][i], bv[jh][j], cur[ih][jh][i][j]);
    }
    __syncthreads();
    if (NPANEL == 2) {
      int ke = kt + 32;
      if (ke == 512) {          // first panel ends: move, restart chain
#pragma unroll
        for (int ih = 0; ih < 2; ++ih)
#pragma unroll
          for (int jh = 0; jh < 2; ++jh)
#pragma unroll
            for (int i = 0; i < 4; ++i)
#pragma unroll
              for (int j = 0; j < 4; ++j) {
                tot[ih][jh][i][j] = cur[ih][jh][i][j];
                cur[ih][jh][i][j] = 0.f;
              }
      }
    }
  }
#pragma unroll
  for (int ih = 0; ih < 2; ++ih)
#pragma unroll
    for (int i = 0; i < 4; ++i) {
      size_t gm = m0 + 64 * ih + 4 * tm + i;
#pragma unroll
      for (int jh = 0; jh < 2; ++jh) {
        size_t gn = n0 + 64 * jh + 4 * tn;
        float rv[4];
#pragma unroll
        for (int j = 0; j < 4; ++j) {
          float v = (NPANEL == 2) ? (tot[ih][jh][i][j] + cur[ih][jh][i][j])
                                  : cur[ih][jh][i][j];
          v = v + bias[gn + j];
          if (MODE == 0) {
            v = v > 0.f ? v : 0.f;
          } else {
            v = resid[gm * (size_t)Nn + gn + j] + v;
          }
          rv[j] = v;
        }
        float4 res = {rv[0], rv[1], rv[2], rv[3]};
        *(float4*)(C + gm * (size_t)Nn + gn) = res;
      }
    }
}

// ---------------- symmetric sim GEMM: upper-tri blocks, write tile + mirror -------
__global__ __launch_bounds__(256, 4) void gemmsym(
    const float* __restrict__ F, float* __restrict__ C)
{
  __shared__ __align__(16) char shraw[33792];
  float (*As)[132] = (float (*)[132])shraw;
  float (*Bs)[132] = (float (*)[132])(shraw + 16896);
  float4* Ts = (float4*)shraw;              // aliased after k-loop (As/Bs dead)

  const int t = threadIdx.x;
  const int tn = t & 15, tm = t >> 4;

  // decode linear block -> (bi, bj), bi<=bj
  int lin = blockIdx.x;
  int bi = (int)(NB + 0.5 - sqrt((NB + 0.5) * (NB + 0.5) - 2.0 * (double)lin));
  if (bi < 0) bi = 0;
  if (bi > NB - 1) bi = NB - 1;
  while (bi + 1 <= NB - 1 && (bi + 1) * NB - ((bi + 1) * bi) / 2 <= lin) ++bi;
  while (bi * NB - (bi * (bi - 1)) / 2 > lin) --bi;
  int bj = bi + (lin - (bi * NB - (bi * (bi - 1)) / 2));

  const size_t m0 = (size_t)bi * 128, n0 = (size_t)bj * 128;

  float cur[2][2][4][4] = {};

  for (int kt = 0; kt < DFEAT; kt += 32) {
#pragma unroll
    for (int u = 0; u < 4; ++u) {
      int f = u * 256 + t;
      int r = f >> 3, c = f & 7;
      int pm = (r & 3) + 4 * ((r >> 2) ^ c);
      float4 va = *(const float4*)(F + (m0 + r) * (size_t)DFEAT + kt + 4 * c);
      As[4 * c + 0][pm] = va.x; As[4 * c + 1][pm] = va.y;
      As[4 * c + 2][pm] = va.z; As[4 * c + 3][pm] = va.w;
      float4 vb = *(const float4*)(F + (n0 + r) * (size_t)DFEAT + kt + 4 * c);
      Bs[4 * c + 0][pm] = vb.x; Bs[4 * c + 1][pm] = vb.y;
      Bs[4 * c + 2][pm] = vb.z; Bs[4 * c + 3][pm] = vb.w;
    }
    __syncthreads();
#pragma unroll 4
    for (int kk = 0; kk < 32; ++kk) {
      const int key = kk >> 2;
      float4 a0 = *(const float4*)&As[kk][4 * (tm ^ key)];
      float4 a1 = *(const float4*)&As[kk][4 * (16 + (tm ^ key))];
      float4 b0 = *(const float4*)&Bs[kk][4 * (tn ^ key)];
      float4 b1 = *(const float4*)&Bs[kk][4 * (16 + (tn ^ key))];
      float av[2][4] = {{a0.x, a0.y, a0.z, a0.w}, {a1.x, a1.y, a1.z, a1.w}};
      float bv[2][4] = {{b0.x, b0.y, b0.z, b0.w}, {b1.x, b1.y, b1.z, b1.w}};
#pragma unroll
      for (int ih = 0; ih < 2; ++ih)
#pragma unroll
        for (int jh = 0; jh < 2; ++jh)
#pragma unroll
          for (int i = 0; i < 4; ++i)
#pragma unroll
            for (int j = 0; j < 4; ++j)
              cur[ih][jh][i][j] = fmaf(av[ih][i], bv[jh][j], cur[ih][jh][i][j]);
    }
    __syncthreads();
  }

  // relu in place
#pragma unroll
  for (int ih = 0; ih < 2; ++ih)
#pragma unroll
    for (int jh = 0; jh < 2; ++jh)
#pragma unroll
      for (int i = 0; i < 4; ++i)
#pragma unroll
        for (int j = 0; j < 4; ++j)
          cur[ih][jh][i][j] = cur[ih][jh][i][j] > 0.f ? cur[ih][jh][i][j] : 0.f;

  // normal tile write (coalesced 256B segments)
#pragma unroll
  for (int ih = 0; ih < 2; ++ih)
#pragma unroll
    for (int i = 0; i < 4; ++i) {
      size_t gm = m0 + 64 * ih + 4 * tm + i;
#pragma unroll
      for (int jh = 0; jh < 2; ++jh) {
        float4 res = {cur[ih][jh][i][0], cur[ih][jh][i][1],
                      cur[ih][jh][i][2], cur[ih][jh][i][3]};
        *(float4*)(C + gm * (size_t)NROW + n0 + 64 * jh + 4 * tn) = res;
      }
    }

  // mirrored tile: LDS transpose (64 rows per jh-chunk), then coalesced stores
  if (bi != bj) {
#pragma unroll
    for (int jh = 0; jh < 2; ++jh) {
      __syncthreads();
#pragma unroll
      for (int ih = 0; ih < 2; ++ih)
#pragma unroll
        for (int j = 0; j < 4; ++j) {
          int rowl = 4 * tn + j;
          int slot = 16 * ih + tm;
          int phys = slot ^ (rowl >> 2);
          Ts[rowl * 32 + phys] =
              make_float4(cur[ih][jh][0][j], cur[ih][jh][1][j],
                          cur[ih][jh][2][j], cur[ih][jh][3][j]);
        }
      __syncthreads();
      {
        int rowr = t >> 2;
        size_t gn = n0 + 64 * jh + rowr;
#pragma unroll
        for (int q = 0; q < 8; ++q) {
          int s = (t & 3) + 4 * q;
          int phys = s ^ (rowr >> 2);
          float4 v = Ts[rowr * 32 + phys];
          *(float4*)(C + gn * (size_t)NROW + m0 + 4 * s) = v;
        }
      }
    }
  }
}

// ---------------- norm + fn: numpy classic pairwise (UNCHANGED, bit-critical) -----
__global__ __launch_bounds__(256) void norm_fn_kernel(const float* __restrict__ feat,
                                                      float* __restrict__ fn) {
#pragma clang fp contract(off)
  const int row = blockIdx.x * 4 + (threadIdx.x >> 6);
  const int lane = threadIdx.x & 63;
  const float* fr = feat + (size_t)row * DFEAT;
  float r = 0.f;
  if (lane < 32) {
    const float* bp = fr + (lane >> 3) * 128 + (lane & 7);
    float x = bp[0];
    r = x * x;
#pragma unroll
    for (int i = 8; i <= 120; i += 8) {
      float x2 = bp[i];
      float s = x2 * x2;
      r = r + s;
    }
  }
  float v[32];
#pragma unroll
  for (int j = 0; j < 32; ++j) v[j] = __shfl(r, j);
  float Bv[4];
#pragma unroll
  for (int b = 0; b < 4; ++b) {
    const float* p = v + 8 * b;
    Bv[b] = ((p[0] + p[1]) + (p[2] + p[3])) + ((p[4] + p[5]) + (p[6] + p[7]));
  }
  float S = (Bv[0] + Bv[1]) + (Bv[2] + Bv[3]);
  float den = (float)sqrt((double)S) + 1e-8f;
#pragma unroll
  for (int e = 0; e < 8; ++e) {
    int d = e * 64 + lane;
    fn[(size_t)row * DFEAT + d] = fr[d] / den;
  }
}

// ---------------- per-row top-32 v3: stream + compact-candidate radix ------------
// st: [0] prefix, [1] needed, [2] shortfall, [3] out count, [4] chosen-bin count,
//     [5] list count
__device__ __forceinline__ void radix_scan(const unsigned int (*h4)[256], int* st, int t) {
  if (t < 64) {
    int h0 = (int)(h4[0][4 * t + 0] + h4[1][4 * t + 0] + h4[2][4 * t + 0] + h4[3][4 * t + 0]);
    int h1 = (int)(h4[0][4 * t + 1] + h4[1][4 * t + 1] + h4[2][4 * t + 1] + h4[3][4 * t + 1]);
    int h2 = (int)(h4[0][4 * t + 2] + h4[1][4 * t + 2] + h4[2][4 * t + 2] + h4[3][4 * t + 2]);
    int h3 = (int)(h4[0][4 * t + 3] + h4[1][4 * t + 3] + h4[2][4 * t + 3] + h4[3][4 * t + 3]);
    int S = h0 + h1 + h2 + h3;
#pragma unroll
    for (int off = 1; off < 64; off <<= 1) {
      int o = __shfl_down(S, off);
      if (t + off < 64) S += o;
    }
    int Sn = __shfl_down(S, 1);
    if (t == 63) Sn = 0;
    int needed = st[1];
    if (S >= needed && Sn < needed) {
      int cg = Sn, b, hb;
      if (cg + h3 >= needed) { b = 3; hb = h3; }
      else if ((cg += h3) + h2 >= needed) { b = 2; hb = h2; }
      else if ((cg += h2) + h1 >= needed) { b = 1; hb = h1; }
      else { cg += h1; b = 0; hb = h0; }
      st[0] = (st[0] << 8) | (4 * t + b);
      st[1] = needed - cg;
      st[4] = hb;
    }
    if (t == 0 && S < needed) { st[2] = 1; st[1] = needed - S; }
  }
}

__global__ __launch_bounds__(256, 4) void topk_kernel(
    float* __restrict__ sim, float* __restrict__ topv, int* __restrict__ topi)
{
  __shared__ unsigned int hist4[4][256];   // 4 KiB per-wave histograms
  __shared__ u64 list[LISTCAP];            // 24 KiB threshold-bin candidates
  __shared__ int st[8];
  __shared__ int smin[4];
  const int row = blockIdx.x, t = threadIdx.x;
  float4* rp = (float4*)(sim + (size_t)row * NROW);
  unsigned int* myh = hist4[t >> 6];
  const float4 z4 = make_float4(0.f, 0.f, 0.f, 0.f);

#pragma unroll
  for (int w = 0; w < 4; ++w) hist4[w][t] = 0;
  if (t == 0) { st[0] = 0; st[1] = 32; st[2] = 0; st[3] = 0; st[5] = 0; }
  __syncthreads();

  // ---- pass 1: stream row, top-byte histogram (skip exact zeros) ----
#pragma unroll 4
  for (int it = 0; it < 12; ++it) {
    float4 v = rp[t + 256 * it];
    unsigned w0 = __float_as_uint(v.x), w1 = __float_as_uint(v.y),
             w2 = __float_as_uint(v.z), w3 = __float_as_uint(v.w);
    if (w0) atomicAdd(&myh[w0 >> 24], 1u);
    if (w1) atomicAdd(&myh[w1 >> 24], 1u);
    if (w2) atomicAdd(&myh[w2 >> 24], 1u);
    if (w3) atomicAdd(&myh[w3 >> 24], 1u);
  }
  __syncthreads();
  radix_scan(hist4, st, t);
  __syncthreads();

  if (st[2] == 0) {
    const unsigned b3 = (unsigned)st[0];     // threshold top byte
    const int C = st[4];                     // exact count in that bin
    const bool uselist = (C <= LISTCAP);

    // ---- pass 2: re-read (cache-hot); emit byte>b3; compact byte==b3; zero ----
#pragma unroll 4
    for (int it = 0; it < 12; ++it) {
      int q = t + 256 * it;
      float4 v = rp[q];
      if (uselist) rp[q] = z4;               // fused zero (only when done with row)
      unsigned ws[4] = {__float_as_uint(v.x), __float_as_uint(v.y),
                        __float_as_uint(v.z), __float_as_uint(v.w)};
      int jb = 4 * q;
#pragma unroll
      for (int e = 0; e < 4; ++e) {
        unsigned w = ws[e];
        if (!w) continue;
        unsigned b = w >> 24;
        if (b > b3) {
          int pos = atomicAdd(&st[3], 1);
          topv[row * 32 + pos] = __uint_as_float(w);
          topi[row * 32 + pos] = jb + e;
        } else if (b == b3 && uselist) {
          int p = atomicAdd(&st[5], 1);
          list[p] = ((u64)w << 32) | (unsigned)(jb + e);
        }
      }
    }
    __syncthreads();

    if (uselist) {
      const int nL = st[5];
      // ---- radix bytes 2,1,0 over the tiny list ----
      for (int p = 1; p < 4; ++p) {
        unsigned pref = (unsigned)st[0];
        const int sh = 24 - 8 * p;
#pragma unroll
        for (int w = 0; w < 4; ++w) hist4[w][t] = 0;
        __syncthreads();
        for (int i = t; i < nL; i += 256) {
          unsigned w = (unsigned)(list[i] >> 32);
          if ((w >> (sh + 8)) == pref) atomicAdd(&myh[(w >> sh) & 255u], 1u);
        }
        __syncthreads();
        radix_scan(hist4, st, t);
        __syncthreads();
      }
      const unsigned T = (unsigned)st[0];
      const int r = st[1];
      // emit list entries strictly above T
      for (int i = t; i < nL; i += 256) {
        unsigned w = (unsigned)(list[i] >> 32);
        if (w > T) {
          int pos = atomicAdd(&st[3], 1);
          topv[row * 32 + pos] = __uint_as_float(w);
          topi[row * 32 + pos] = (int)(unsigned)list[i];
        }
      }
      // r smallest-index ties at T (matches ~idx key tie-break)
      int last = -1;
      const int base = 32 - r;
      for (int rd = 0; rd < r; ++rd) {
        int lm = 0x7fffffff;
        for (int i = t; i < nL; i += 256) {
          unsigned w = (unsigned)(list[i] >> 32);
          int j = (int)(unsigned)list[i];
          if (w == T && j > last && j < lm) lm = j;
        }
#pragma unroll
        for (int off = 32; off >= 1; off >>= 1) {
          int o = __shfl_xor(lm, off);
          if (o < lm) lm = o;
        }
        if ((t & 63) == 0) smin[t >> 6] = lm;
        __syncthreads();
        int g0 = smin[0] < smin[1] ? smin[0] : smin[1];
        int g1 = smin[2] < smin[3] ? smin[2] : smin[3];
        int g = g0 < g1 ? g0 : g1;
        if (t == 0) {
          topv[row * 32 + base + rd] = __uint_as_float(T);
          topi[row * 32 + base + rd] = g;
        }
        last = g;
        __syncthreads();
      }
    } else {
      // ---- fallback C > LISTCAP (rare): refine via global re-reads; zero last ----
      for (int p = 1; p < 4; ++p) {
        unsigned pref = (unsigned)st[0];
        const int sh = 24 - 8 * p;
#pragma unroll
        for (int w = 0; w < 4; ++w) hist4[w][t] = 0;
        __syncthreads();
#pragma unroll 4
        for (int it = 0; it < 12; ++it) {
          float4 v = rp[t + 256 * it];
          unsigned ws[4] = {__float_as_uint(v.x), __float_as_uint(v.y),
                            __float_as_uint(v.z), __float_as_uint(v.w)};
#pragma unroll
          for (int e = 0; e < 4; ++e)
            if (ws[e] && (ws[e] >> (sh + 8)) == pref)
              atomicAdd(&myh[(ws[e] >> sh) & 255u], 1u);
        }
        __syncthreads();
        radix_scan(hist4, st, t);
        __syncthreads();
      }
      const unsigned T = (unsigned)st[0];
      const int r = st[1];
      // emit w>T within the b3 bin (byte>b3 already emitted in pass 2)
#pragma unroll 4
      for (int it = 0; it < 12; ++it) {
        int q = t + 256 * it;
        float4 v = rp[q];
        unsigned ws[4] = {__float_as_uint(v.x), __float_as_uint(v.y),
                          __float_as_uint(v.z), __float_as_uint(v.w)};
        int jb = 4 * q;
#pragma unroll
        for (int e = 0; e < 4; ++e) {
          unsigned w = ws[e];
          if (w > T && (w >> 24) == b3) {
            int pos = atomicAdd(&st[3], 1);
            topv[row * 32 + pos] = __uint_as_float(w);
            topi[row * 32 + pos] = jb + e;
          }
        }
      }
      // ties at T over global
      int last = -1;
      const int base = 32 - r;
      for (int rd = 0; rd < r; ++rd) {
        int lm = 0x7fffffff;
#pragma unroll 4
        for (int it = 0; it < 12; ++it) {
          int q = t + 256 * it;
          float4 v = rp[q];
          unsigned ws[4] = {__float_as_uint(v.x), __float_as_uint(v.y),
                            __float_as_uint(v.z), __float_as_uint(v.w)};
          int jb = 4 * q;
#pragma unroll
          for (int e = 0; e < 4; ++e) {
            int j = jb + e;
            if (ws[e] == T && j > last && j < lm) lm = j;
          }
        }
#pragma unroll
        for (int off = 32; off >= 1; off >>= 1) {
          int o = __shfl_xor(lm, off);
          if (o < lm) lm = o;
        }
        if ((t & 63) == 0) smin[t >> 6] = lm;
        __syncthreads();
        int g0 = smin[0] < smin[1] ? smin[0] : smin[1];
        int g1 = smin[2] < smin[3] ? smin[2] : smin[3];
        int g = g0 < g1 ? g0 : g1;
        if (t == 0) {
          topv[row * 32 + base + rd] = __uint_as_float(T);
          topi[row * 32 + base + rd] = g;
        }
        last = g;
        __syncthreads();
      }
      // zero row now that all reads are done
#pragma unroll 4
      for (int it = 0; it < 12; ++it) rp[t + 256 * it] = z4;
    }
  } else {
    // ---- shortfall: fewer than 32 nonzeros (never on this data; exact path) ----
#pragma unroll 4
    for (int it = 0; it < 12; ++it) {
      int q = t + 256 * it;
      float4 v = rp[q];
      unsigned ws[4] = {__float_as_uint(v.x), __float_as_uint(v.y),
                        __float_as_uint(v.z), __float_as_uint(v.w)};
      int jb = 4 * q;
#pragma unroll
      for (int e = 0; e < 4; ++e)
        if (ws[e]) {
          int pos = atomicAdd(&st[3], 1);
          topv[row * 32 + pos] = __uint_as_float(ws[e]);
          topi[row * 32 + pos] = jb + e;
        }
    }
    __syncthreads();
    const int r = st[1];
    const int base = 32 - r;
    if (t == 0) {   // r smallest zero indices, serial exact (cold path)
      const float* rf = (const float*)rp;
      int cnt = 0;
      for (int j = 0; j < NROW && cnt < r; ++j)
        if (__float_as_uint(rf[j]) == 0u) {
          topv[row * 32 + base + cnt] = 0.f;
          topi[row * 32 + base + cnt] = j;
          ++cnt;
        }
    }
    __syncthreads();
#pragma unroll 4
    for (int it = 0; it < 12; ++it) rp[t + 256 * it] = z4;
  }
}

// ---------------- scatter ----------------
__global__ __launch_bounds__(256) void scatter_kernel(
    const float* __restrict__ topv, const int* __restrict__ topi, float* __restrict__ out) {
  int g = blockIdx.x * 256 + threadIdx.x;
  int row = g >> 5;
  float v = 0.5f * topv[g];
  int j = topi[g];
  atomicAdd(out + (size_t)row * NROW + j, v);
  atomicAdd(out + (size_t)j * NROW + row, v);
}

// ---------------- launch ----------------
extern "C" void kernel_launch(void* const* d_in, const int* in_sizes, int n_in,
                              void* d_out, int out_size, void* d_ws, size_t ws_size,
                              hipStream_t stream)
{
  const float* X  = (const float*)d_in[0];
  const float* W1 = (const float*)d_in[1];
  const float* b1 = (const float*)d_in[2];
  const float* W2 = (const float*)d_in[3];
  const float* b2 = (const float*)d_in[4];
  const float* W3 = (const float*)d_in[5];
  const float* b3 = (const float*)d_in[6];
  float* out = (float*)d_out;

  char* ws = (char*)d_ws;
  size_t off = 0;
  auto carve = [&](size_t bytes) {
    char* p = ws + off;
    off += (bytes + 255) & ~(size_t)255;
    return (void*)p;
  };

  float* h1   = (float*)carve(4ull * NROW * HDIM);
  float* h2   = (float*)carve(4ull * NROW * HDIM);
  float* feat = (float*)carve(4ull * NROW * DFEAT);
  float* fn   = (float*)carve(4ull * NROW * DFEAT);
  float* topv = (float*)carve(4ull * NROW * 32);
  int*   topi = (int*)carve(4ull * NROW * 32);

  // MLP (chains bit-identical to round 9: K=512 single, K=1024 -> (512,512))
  gemm128<0, 1><<<dim3(HDIM / 128, NROW / 128), 256, 0, stream>>>(
      X, W1, b1, nullptr, h1, HDIM, DFEAT);
  gemm128<0, 2><<<dim3(HDIM / 128, NROW / 128), 256, 0, stream>>>(
      h1, W2, b2, nullptr, h2, HDIM, HDIM);
  gemm128<1, 2><<<dim3(DFEAT / 128, NROW / 128), 256, 0, stream>>>(
      h2, W3, b3, X, feat, DFEAT, HDIM);

  // norm + fn
  norm_fn_kernel<<<NROW / 4, 256, 0, stream>>>(feat, fn);

  // sim = relu(fn @ fn^T), symmetric: 4656 upper-tri blocks
  gemmsym<<<dim3(NB * (NB + 1) / 2), 256, 0, stream>>>(fn, out);

  // top-32 per row + fused zeroing of each row
  topk_kernel<<<NROW, 256, 0, stream>>>(out, topv, topi);

  // symmetric scatter into the (now zeroed) output
  scatter_kernel<<<(NROW * 32) / 256, 256, 0, stream>>>(topv, topi, out);
}

// Round 13
// 2784.588 us; speedup vs baseline: 1.0208x; 1.0208x over previous
//
#include <hip/hip_runtime.h>
#include <stdint.h>
#include <math.h>

typedef unsigned long long u64;

#define NROW 12288
#define DFEAT 512
#define HDIM  1024
#define NB    96   // NROW/128

// ==================================================================================
// NUMERICS CONTRACT (validated round 9, absmax 1.95e-3):
//   - every GEMM C element = single-accumulator FMA chain, k ascending, in panels
//     (512) for K=512 and (512,512) for K=1024, panels merged with one f32 add;
//   - norm = numpy classic pairwise (unchanged);
//   - top-32: exact byte-radix select (same selected SET as u64-key pop loop);
//     0.5v+0.5v symmetric scatter unchanged.
// Round 13 (= round 12 resubmit; container infra failure, not a kernel verdict):
// round-10 best-measured base (2749us) + ONE change: gemm128 __launch_bounds__
// (256,3) -> (256,4), matching gemmsym's proven config (r7 measured this exact
// knob on gemmsym: 4->3 cost 35us via occupancy 41->31%).
// LDS 33792B x 4 = 135KB <= 160KB; VGPR 64 <= 128/wave at 4 waves/SIMD.
// topk = r10 svb version (r11's compact-list v3 regressed ~70us).
// Chains bit-identical.
// ==================================================================================

// ---------------- MLP GEMM: 128x128 tile, 8x8/thread (2x2 groups of 4x4) ----------
template <int MODE, int NPANEL>
__global__ __launch_bounds__(256, 4) void gemm128(
    const float* __restrict__ A, const float* __restrict__ B,
    const float* __restrict__ bias, const float* __restrict__ resid,
    float* __restrict__ C, int Nn, int K)
{
  __shared__ float As[32][132];   // [k][m], XOR-swizzled m-groups
  __shared__ float Bs[32][132];   // [k][n]
  const int t = threadIdx.x;
  const int tn = t & 15, tm = t >> 4;
  const size_t m0 = (size_t)blockIdx.y * 128, n0 = (size_t)blockIdx.x * 128;

  float cur[2][2][4][4] = {};             // [ih][jh][i][j]
  float tot[2][2][4][4];                  // used only when NPANEL==2

  for (int kt = 0; kt < K; kt += 32) {
#pragma unroll
    for (int u = 0; u < 4; ++u) {
      int f = u * 256 + t;
      int r = f >> 3, c = f & 7;
      int pm = (r & 3) + 4 * ((r >> 2) ^ c);   // swizzled m-slot (bijective per k-row)
      float4 va = *(const float4*)(A + (m0 + r) * (size_t)K + kt + 4 * c);
      As[4 * c + 0][pm] = va.x; As[4 * c + 1][pm] = va.y;
      As[4 * c + 2][pm] = va.z; As[4 * c + 3][pm] = va.w;
      float4 vb = *(const float4*)(B + (n0 + r) * (size_t)K + kt + 4 * c);
      Bs[4 * c + 0][pm] = vb.x; Bs[4 * c + 1][pm] = vb.y;
      Bs[4 * c + 2][pm] = vb.z; Bs[4 * c + 3][pm] = vb.w;
    }
    __syncthreads();
#pragma unroll 4
    for (int kk = 0; kk < 32; ++kk) {
      const int key = kk >> 2;
      float4 a0 = *(const float4*)&As[kk][4 * (tm ^ key)];
      float4 a1 = *(const float4*)&As[kk][4 * (16 + (tm ^ key))];
      float4 b0 = *(const float4*)&Bs[kk][4 * (tn ^ key)];
      float4 b1 = *(const float4*)&Bs[kk][4 * (16 + (tn ^ key))];
      float av[2][4] = {{a0.x, a0.y, a0.z, a0.w}, {a1.x, a1.y, a1.z, a1.w}};
      float bv[2][4] = {{b0.x, b0.y, b0.z, b0.w}, {b1.x, b1.y, b1.z, b1.w}};
#pragma unroll
      for (int ih = 0; ih < 2; ++ih)
#pragma unroll
        for (int jh = 0; jh < 2; ++jh)
#pragma unroll
          for (int i = 0; i < 4; ++i)
#pragma unroll
            for (int j = 0; j < 4; ++j)
              cur[ih][jh][i][j] = fmaf(av[ih][i], bv[jh][j], cur[ih][jh][i][j]);
    }
    __syncthreads();
    if (NPANEL == 2) {
      int ke = kt + 32;
      if (ke == 512) {          // first panel ends: move, restart chain
#pragma unroll
        for (int ih = 0; ih < 2; ++ih)
#pragma unroll
          for (int jh = 0; jh < 2; ++jh)
#pragma unroll
            for (int i = 0; i < 4; ++i)
#pragma unroll
              for (int j = 0; j < 4; ++j) {
                tot[ih][jh][i][j] = cur[ih][jh][i][j];
                cur[ih][jh][i][j] = 0.f;
              }
      }
    }
  }
#pragma unroll
  for (int ih = 0; ih < 2; ++ih)
#pragma unroll
    for (int i = 0; i < 4; ++i) {
      size_t gm = m0 + 64 * ih + 4 * tm + i;
#pragma unroll
      for (int jh = 0; jh < 2; ++jh) {
        size_t gn = n0 + 64 * jh + 4 * tn;
        float rv[4];
#pragma unroll
        for (int j = 0; j < 4; ++j) {
          float v = (NPANEL == 2) ? (tot[ih][jh][i][j] + cur[ih][jh][i][j])
                                  : cur[ih][jh][i][j];
          v = v + bias[gn + j];
          if (MODE == 0) {
            v = v > 0.f ? v : 0.f;
          } else {
            v = resid[gm * (size_t)Nn + gn + j] + v;
          }
          rv[j] = v;
        }
        float4 res = {rv[0], rv[1], rv[2], rv[3]};
        *(float4*)(C + gm * (size_t)Nn + gn) = res;
      }
    }
}

// ---------------- symmetric sim GEMM: upper-tri blocks, write tile + mirror -------
// Mirror path: LDS float4-transpose (XOR-swizzled) -> coalesced 64B-segment stores.
__global__ __launch_bounds__(256, 4) void gemmsym(
    const float* __restrict__ F, float* __restrict__ C)
{
  __shared__ __align__(16) char shraw[33792];
  float (*As)[132] = (float (*)[132])shraw;
  float (*Bs)[132] = (float (*)[132])(shraw + 16896);
  float4* Ts = (float4*)shraw;              // aliased after k-loop (As/Bs dead)

  const int t = threadIdx.x;
  const int tn = t & 15, tm = t >> 4;

  // decode linear block -> (bi, bj), bi<=bj
  int lin = blockIdx.x;
  int bi = (int)(NB + 0.5 - sqrt((NB + 0.5) * (NB + 0.5) - 2.0 * (double)lin));
  if (bi < 0) bi = 0;
  if (bi > NB - 1) bi = NB - 1;
  while (bi + 1 <= NB - 1 && (bi + 1) * NB - ((bi + 1) * bi) / 2 <= lin) ++bi;
  while (bi * NB - (bi * (bi - 1)) / 2 > lin) --bi;
  int bj = bi + (lin - (bi * NB - (bi * (bi - 1)) / 2));

  const size_t m0 = (size_t)bi * 128, n0 = (size_t)bj * 128;

  float cur[2][2][4][4] = {};

  for (int kt = 0; kt < DFEAT; kt += 32) {
#pragma unroll
    for (int u = 0; u < 4; ++u) {
      int f = u * 256 + t;
      int r = f >> 3, c = f & 7;
      int pm = (r & 3) + 4 * ((r >> 2) ^ c);
      float4 va = *(const float4*)(F + (m0 + r) * (size_t)DFEAT + kt + 4 * c);
      As[4 * c + 0][pm] = va.x; As[4 * c + 1][pm] = va.y;
      As[4 * c + 2][pm] = va.z; As[4 * c + 3][pm] = va.w;
      float4 vb = *(const float4*)(F + (n0 + r) * (size_t)DFEAT + kt + 4 * c);
      Bs[4 * c + 0][pm] = vb.x; Bs[4 * c + 1][pm] = vb.y;
      Bs[4 * c + 2][pm] = vb.z; Bs[4 * c + 3][pm] = vb.w;
    }
    __syncthreads();
#pragma unroll 4
    for (int kk = 0; kk < 32; ++kk) {
      const int key = kk >> 2;
      float4 a0 = *(const float4*)&As[kk][4 * (tm ^ key)];
      float4 a1 = *(const float4*)&As[kk][4 * (16 + (tm ^ key))];
      float4 b0 = *(const float4*)&Bs[kk][4 * (tn ^ key)];
      float4 b1 = *(const float4*)&Bs[kk][4 * (16 + (tn ^ key))];
      float av[2][4] = {{a0.x, a0.y, a0.z, a0.w}, {a1.x, a1.y, a1.z, a1.w}};
      float bv[2][4] = {{b0.x, b0.y, b0.z, b0.w}, {b1.x, b1.y, b1.z, b1.w}};
#pragma unroll
      for (int ih = 0; ih < 2; ++ih)
#pragma unroll
        for (int jh = 0; jh < 2; ++jh)
#pragma unroll
          for (int i = 0; i < 4; ++i)
#pragma unroll
            for (int j = 0; j < 4; ++j)
              cur[ih][jh][i][j] = fmaf(av[ih][i], bv[jh][j], cur[ih][jh][i][j]);
    }
    __syncthreads();
  }

  // relu in place
#pragma unroll
  for (int ih = 0; ih < 2; ++ih)
#pragma unroll
    for (int jh = 0; jh < 2; ++jh)
#pragma unroll
      for (int i = 0; i < 4; ++i)
#pragma unroll
        for (int j = 0; j < 4; ++j)
          cur[ih][jh][i][j] = cur[ih][jh][i][j] > 0.f ? cur[ih][jh][i][j] : 0.f;

  // normal tile write (coalesced 256B segments)
#pragma unroll
  for (int ih = 0; ih < 2; ++ih)
#pragma unroll
    for (int i = 0; i < 4; ++i) {
      size_t gm = m0 + 64 * ih + 4 * tm + i;
#pragma unroll
      for (int jh = 0; jh < 2; ++jh) {
        float4 res = {cur[ih][jh][i][0], cur[ih][jh][i][1],
                      cur[ih][jh][i][2], cur[ih][jh][i][3]};
        *(float4*)(C + gm * (size_t)NROW + n0 + 64 * jh + 4 * tn) = res;
      }
    }

  // mirrored tile: LDS transpose (64 rows per jh-chunk), then coalesced stores
  if (bi != bj) {
#pragma unroll
    for (int jh = 0; jh < 2; ++jh) {
      __syncthreads();   // previous chunk reads (or k-loop/As reads) complete
#pragma unroll
      for (int ih = 0; ih < 2; ++ih)
#pragma unroll
        for (int j = 0; j < 4; ++j) {
          int rowl = 4 * tn + j;              // mirror-row within chunk, 0..63
          int slot = 16 * ih + tm;            // float4-slot along mirror row, 0..31
          int phys = slot ^ (rowl >> 2);      // conflict-free swizzle
          Ts[rowl * 32 + phys] =
              make_float4(cur[ih][jh][0][j], cur[ih][jh][1][j],
                          cur[ih][jh][2][j], cur[ih][jh][3][j]);
        }
      __syncthreads();
      {
        int rowr = t >> 2;                    // 0..63
        size_t gn = n0 + 64 * jh + rowr;
#pragma unroll
        for (int q = 0; q < 8; ++q) {
          int s = (t & 3) + 4 * q;            // logical slot: 64B contiguous / 4 lanes
          int phys = s ^ (rowr >> 2);
          float4 v = Ts[rowr * 32 + phys];
          *(float4*)(C + gn * (size_t)NROW + m0 + 4 * s) = v;
        }
      }
    }
  }
}

// ---------------- norm + fn: numpy classic pairwise (UNCHANGED, bit-critical) -----
__global__ __launch_bounds__(256) void norm_fn_kernel(const float* __restrict__ feat,
                                                      float* __restrict__ fn) {
#pragma clang fp contract(off)
  const int row = blockIdx.x * 4 + (threadIdx.x >> 6);
  const int lane = threadIdx.x & 63;
  const float* fr = feat + (size_t)row * DFEAT;
  float r = 0.f;
  if (lane < 32) {
    const float* bp = fr + (lane >> 3) * 128 + (lane & 7);
    float x = bp[0];
    r = x * x;
#pragma unroll
    for (int i = 8; i <= 120; i += 8) {
      float x2 = bp[i];
      float s = x2 * x2;
      r = r + s;
    }
  }
  float v[32];
#pragma unroll
  for (int j = 0; j < 32; ++j) v[j] = __shfl(r, j);
  float Bv[4];
#pragma unroll
  for (int b = 0; b < 4; ++b) {
    const float* p = v + 8 * b;
    Bv[b] = ((p[0] + p[1]) + (p[2] + p[3])) + ((p[4] + p[5]) + (p[6] + p[7]));
  }
  float S = (Bv[0] + Bv[1]) + (Bv[2] + Bv[3]);
  float den = (float)sqrt((double)S) + 1e-8f;
#pragma unroll
  for (int e = 0; e < 8; ++e) {
    int d = e * 64 + lane;
    fn[(size_t)row * DFEAT + d] = fr[d] / den;
  }
}

// ---------------- per-row top-32: exact byte-radix select + fused row-zero -------
// Privatized per-wave histograms; each block zeroes ITS OWN row right after
// staging it to LDS (replaces standalone zero_kernel; lines L2-hot).
__device__ __forceinline__ void radix_scan(const unsigned int (*h4)[256], int* st, int t) {
  if (t < 64) {
    int h0 = (int)(h4[0][4 * t + 0] + h4[1][4 * t + 0] + h4[2][4 * t + 0] + h4[3][4 * t + 0]);
    int h1 = (int)(h4[0][4 * t + 1] + h4[1][4 * t + 1] + h4[2][4 * t + 1] + h4[3][4 * t + 1]);
    int h2 = (int)(h4[0][4 * t + 2] + h4[1][4 * t + 2] + h4[2][4 * t + 2] + h4[3][4 * t + 2]);
    int h3 = (int)(h4[0][4 * t + 3] + h4[1][4 * t + 3] + h4[2][4 * t + 3] + h4[3][4 * t + 3]);
    int S = h0 + h1 + h2 + h3;
#pragma unroll
    for (int off = 1; off < 64; off <<= 1) {
      int o = __shfl_down(S, off);
      if (t + off < 64) S += o;
    }
    int Sn = __shfl_down(S, 1);
    if (t == 63) Sn = 0;
    int needed = st[1];
    if (S >= needed && Sn < needed) {
      int cg = Sn, b;
      if (cg + h3 >= needed) b = 3;
      else if ((cg += h3) + h2 >= needed) b = 2;
      else if ((cg += h2) + h1 >= needed) b = 1;
      else { cg += h1; b = 0; }
      st[0] = (st[0] << 8) | (4 * t + b);
      st[1] = needed - cg;
    }
    if (t == 0 && S < needed) { st[2] = 1; st[1] = needed - S; }
  }
}

__global__ __launch_bounds__(256, 3) void topk_kernel(
    float* __restrict__ sim, float* __restrict__ topv, int* __restrict__ topi)
{
  __shared__ __align__(16) unsigned int svb[NROW];  // 48 KiB: row value bits
  __shared__ unsigned int hist4[4][256];            // per-wave histograms
  __shared__ int st[4];
  __shared__ int smin[4];
  const int row = blockIdx.x, t = threadIdx.x;
  float4* rp = (float4*)(sim + (size_t)row * NROW);
  unsigned int* myh = hist4[t >> 6];

#pragma unroll
  for (int w = 0; w < 4; ++w) hist4[w][t] = 0;
  if (t == 0) { st[0] = 0; st[1] = 32; st[2] = 0; st[3] = 0; }
  __syncthreads();

  const float4 z4 = make_float4(0.f, 0.f, 0.f, 0.f);
#pragma unroll
  for (int it = 0; it < 12; ++it) {
    int q = t + 256 * it;
    float4 v = rp[q];
    unsigned w0 = __float_as_uint(v.x), w1 = __float_as_uint(v.y),
             w2 = __float_as_uint(v.z), w3 = __float_as_uint(v.w);
    uint4 u; u.x = w0; u.y = w1; u.z = w2; u.w = w3;
    *(uint4*)&svb[4 * q] = u;
    rp[q] = z4;                     // fused zero: own row, L2-hot, no cold RFO
    if (w0) atomicAdd(&myh[w0 >> 24], 1u);
    if (w1) atomicAdd(&myh[w1 >> 24], 1u);
    if (w2) atomicAdd(&myh[w2 >> 24], 1u);
    if (w3) atomicAdd(&myh[w3 >> 24], 1u);
  }
  __syncthreads();
  radix_scan(hist4, st, t);
  __syncthreads();

  for (int p = 1; p < 4; ++p) {
    if (st[2]) break;
    unsigned pref = (unsigned)st[0];
    const int sh = 24 - 8 * p;
#pragma unroll
    for (int w = 0; w < 4; ++w) hist4[w][t] = 0;
    __syncthreads();
#pragma unroll
    for (int it = 0; it < 12; ++it) {
      uint4 u = *(const uint4*)&svb[4 * (t + 256 * it)];
      unsigned ws[4] = {u.x, u.y, u.z, u.w};
#pragma unroll
      for (int e = 0; e < 4; ++e)
        if ((ws[e] >> (sh + 8)) == pref)
          atomicAdd(&myh[(ws[e] >> sh) & 255u], 1u);
    }
    __syncthreads();
    radix_scan(hist4, st, t);
    __syncthreads();
  }

  const unsigned T = (unsigned)st[0];
  const int r = st[1];

#pragma unroll
  for (int it = 0; it < 12; ++it) {
    uint4 u = *(const uint4*)&svb[4 * (t + 256 * it)];
    unsigned ws[4] = {u.x, u.y, u.z, u.w};
#pragma unroll
    for (int e = 0; e < 4; ++e)
      if (ws[e] > T) {
        int pos = atomicAdd(&st[3], 1);
        topv[row * 32 + pos] = __uint_as_float(ws[e]);
        topi[row * 32 + pos] = 4 * (t + 256 * it) + e;
      }
  }

  int last = -1;
  const int base = 32 - r;
  for (int rd = 0; rd < r; ++rd) {
    int lm = 0x7fffffff;
#pragma unroll
    for (int it = 0; it < 12; ++it) {
      uint4 u = *(const uint4*)&svb[4 * (t + 256 * it)];
      unsigned ws[4] = {u.x, u.y, u.z, u.w};
#pragma unroll
      for (int e = 0; e < 4; ++e) {
        int j = 4 * (t + 256 * it) + e;
        if (ws[e] == T && j > last && j < lm) lm = j;
      }
    }
#pragma unroll
    for (int off = 32; off >= 1; off >>= 1) {
      int o = __shfl_xor(lm, off);
      if (o < lm) lm = o;
    }
    if ((t & 63) == 0) smin[t >> 6] = lm;
    __syncthreads();
    int g0 = smin[0] < smin[1] ? smin[0] : smin[1];
    int g1 = smin[2] < smin[3] ? smin[2] : smin[3];
    int g = g0 < g1 ? g0 : g1;
    if (t == 0) {
      topv[row * 32 + base + rd] = __uint_as_float(T);
      topi[row * 32 + base + rd] = g;
    }
    last = g;
    __syncthreads();
  }
}

// ---------------- scatter ----------------
__global__ __launch_bounds__(256) void scatter_kernel(
    const float* __restrict__ topv, const int* __restrict__ topi, float* __restrict__ out) {
  int g = blockIdx.x * 256 + threadIdx.x;
  int row = g >> 5;
  float v = 0.5f * topv[g];
  int j = topi[g];
  atomicAdd(out + (size_t)row * NROW + j, v);
  atomicAdd(out + (size_t)j * NROW + row, v);
}

// ---------------- launch ----------------
extern "C" void kernel_launch(void* const* d_in, const int* in_sizes, int n_in,
                              void* d_out, int out_size, void* d_ws, size_t ws_size,
                              hipStream_t stream)
{
  const float* X  = (const float*)d_in[0];
  const float* W1 = (const float*)d_in[1];
  const float* b1 = (const float*)d_in[2];
  const float* W2 = (const float*)d_in[3];
  const float* b2 = (const float*)d_in[4];
  const float* W3 = (const float*)d_in[5];
  const float* b3 = (const float*)d_in[6];
  float* out = (float*)d_out;

  char* ws = (char*)d_ws;
  size_t off = 0;
  auto carve = [&](size_t bytes) {
    char* p = ws + off;
    off += (bytes + 255) & ~(size_t)255;
    return (void*)p;
  };

  float* h1   = (float*)carve(4ull * NROW * HDIM);
  float* h2   = (float*)carve(4ull * NROW * HDIM);
  float* feat = (float*)carve(4ull * NROW * DFEAT);
  float* fn   = (float*)carve(4ull * NROW * DFEAT);
  float* topv = (float*)carve(4ull * NROW * 32);
  int*   topi = (int*)carve(4ull * NROW * 32);

  // MLP (chains bit-identical to round 9: K=512 single, K=1024 -> (512,512))
  gemm128<0, 1><<<dim3(HDIM / 128, NROW / 128), 256, 0, stream>>>(
      X, W1, b1, nullptr, h1, HDIM, DFEAT);
  gemm128<0, 2><<<dim3(HDIM / 128, NROW / 128), 256, 0, stream>>>(
      h1, W2, b2, nullptr, h2, HDIM, HDIM);
  gemm128<1, 2><<<dim3(DFEAT / 128, NROW / 128), 256, 0, stream>>>(
      h2, W3, b3, X, feat, DFEAT, HDIM);

  // norm + fn
  norm_fn_kernel<<<NROW / 4, 256, 0, stream>>>(feat, fn);

  // sim = relu(fn @ fn^T), symmetric: 4656 upper-tri blocks
  gemmsym<<<dim3(NB * (NB + 1) / 2), 256, 0, stream>>>(fn, out);

  // top-32 per row + fused zeroing of each row
  topk_kernel<<<NROW, 256, 0, stream>>>(out, topv, topi);

  // symmetric scatter into the (now zeroed) output
  scatter_kernel<<<(NROW * 32) / 256, 256, 0, stream>>>(topv, topi, out);
}

// Round 14
// 2745.260 us; speedup vs baseline: 1.0354x; 1.0143x over previous
//
#include <hip/hip_runtime.h>
#include <stdint.h>
#include <math.h>

typedef unsigned long long u64;

#define NROW 12288
#define DFEAT 512
#define HDIM  1024
#define NB    96   // NROW/128

// ==================================================================================
// NUMERICS CONTRACT (validated round 9, absmax 1.95e-3):
//   - every GEMM C element = single-accumulator FMA chain, k ascending, in panels
//     (512) for K=512 and (512,512) for K=1024, panels merged with one f32 add;
//   - norm = numpy classic pairwise (unchanged);
//   - top-32: exact byte-radix select (same selected SET as u64-key pop loop);
//     0.5v+0.5v symmetric scatter unchanged.
// FINAL (round 14) = exact round-10 configuration, the session's best measured
// (2749us): swizzled+padded LDS 128x128 GEMMs (lb 256,3 MLP / 256,4 sym),
// gemmsym upper-triangle + LDS-transposed mirror writes, numpy-pairwise norm,
// radix-select topk with privatized per-wave histograms + fused row-zero,
// symmetric scatter. Structural plateau documented: gemmsym pinned ~915us
// (55% of FP32 issue peak) across 6 variants — 2-barrier-per-K-step VALU GEMM
// ceiling; next lever would be inline-asm counted-vmcnt pipelining (regressed
// in every approximation tried here). Chains bit-identical to round 9.
// ==================================================================================

// ---------------- MLP GEMM: 128x128 tile, 8x8/thread (2x2 groups of 4x4) ----------
template <int MODE, int NPANEL>
__global__ __launch_bounds__(256, 3) void gemm128(
    const float* __restrict__ A, const float* __restrict__ B,
    const float* __restrict__ bias, const float* __restrict__ resid,
    float* __restrict__ C, int Nn, int K)
{
  __shared__ float As[32][132];   // [k][m], XOR-swizzled m-groups
  __shared__ float Bs[32][132];   // [k][n]
  const int t = threadIdx.x;
  const int tn = t & 15, tm = t >> 4;
  const size_t m0 = (size_t)blockIdx.y * 128, n0 = (size_t)blockIdx.x * 128;

  float cur[2][2][4][4] = {};             // [ih][jh][i][j]
  float tot[2][2][4][4];                  // used only when NPANEL==2

  for (int kt = 0; kt < K; kt += 32) {
#pragma unroll
    for (int u = 0; u < 4; ++u) {
      int f = u * 256 + t;
      int r = f >> 3, c = f & 7;
      int pm = (r & 3) + 4 * ((r >> 2) ^ c);   // swizzled m-slot (bijective per k-row)
      float4 va = *(const float4*)(A + (m0 + r) * (size_t)K + kt + 4 * c);
      As[4 * c + 0][pm] = va.x; As[4 * c + 1][pm] = va.y;
      As[4 * c + 2][pm] = va.z; As[4 * c + 3][pm] = va.w;
      float4 vb = *(const float4*)(B + (n0 + r) * (size_t)K + kt + 4 * c);
      Bs[4 * c + 0][pm] = vb.x; Bs[4 * c + 1][pm] = vb.y;
      Bs[4 * c + 2][pm] = vb.z; Bs[4 * c + 3][pm] = vb.w;
    }
    __syncthreads();
#pragma unroll 4
    for (int kk = 0; kk < 32; ++kk) {
      const int key = kk >> 2;
      float4 a0 = *(const float4*)&As[kk][4 * (tm ^ key)];
      float4 a1 = *(const float4*)&As[kk][4 * (16 + (tm ^ key))];
      float4 b0 = *(const float4*)&Bs[kk][4 * (tn ^ key)];
      float4 b1 = *(const float4*)&Bs[kk][4 * (16 + (tn ^ key))];
      float av[2][4] = {{a0.x, a0.y, a0.z, a0.w}, {a1.x, a1.y, a1.z, a1.w}};
      float bv[2][4] = {{b0.x, b0.y, b0.z, b0.w}, {b1.x, b1.y, b1.z, b1.w}};
#pragma unroll
      for (int ih = 0; ih < 2; ++ih)
#pragma unroll
        for (int jh = 0; jh < 2; ++jh)
#pragma unroll
          for (int i = 0; i < 4; ++i)
#pragma unroll
            for (int j = 0; j < 4; ++j)
              cur[ih][jh][i][j] = fmaf(av[ih][i], bv[jh][j], cur[ih][jh][i][j]);
    }
    __syncthreads();
    if (NPANEL == 2) {
      int ke = kt + 32;
      if (ke == 512) {          // first panel ends: move, restart chain
#pragma unroll
        for (int ih = 0; ih < 2; ++ih)
#pragma unroll
          for (int jh = 0; jh < 2; ++jh)
#pragma unroll
            for (int i = 0; i < 4; ++i)
#pragma unroll
              for (int j = 0; j < 4; ++j) {
                tot[ih][jh][i][j] = cur[ih][jh][i][j];
                cur[ih][jh][i][j] = 0.f;
              }
      }
    }
  }
#pragma unroll
  for (int ih = 0; ih < 2; ++ih)
#pragma unroll
    for (int i = 0; i < 4; ++i) {
      size_t gm = m0 + 64 * ih + 4 * tm + i;
#pragma unroll
      for (int jh = 0; jh < 2; ++jh) {
        size_t gn = n0 + 64 * jh + 4 * tn;
        float rv[4];
#pragma unroll
        for (int j = 0; j < 4; ++j) {
          float v = (NPANEL == 2) ? (tot[ih][jh][i][j] + cur[ih][jh][i][j])
                                  : cur[ih][jh][i][j];
          v = v + bias[gn + j];
          if (MODE == 0) {
            v = v > 0.f ? v : 0.f;
          } else {
            v = resid[gm * (size_t)Nn + gn + j] + v;
          }
          rv[j] = v;
        }
        float4 res = {rv[0], rv[1], rv[2], rv[3]};
        *(float4*)(C + gm * (size_t)Nn + gn) = res;
      }
    }
}

// ---------------- symmetric sim GEMM: upper-tri blocks, write tile + mirror -------
// Mirror path: LDS float4-transpose (XOR-swizzled) -> coalesced 64B-segment stores.
__global__ __launch_bounds__(256, 4) void gemmsym(
    const float* __restrict__ F, float* __restrict__ C)
{
  __shared__ __align__(16) char shraw[33792];
  float (*As)[132] = (float (*)[132])shraw;
  float (*Bs)[132] = (float (*)[132])(shraw + 16896);
  float4* Ts = (float4*)shraw;              // aliased after k-loop (As/Bs dead)

  const int t = threadIdx.x;
  const int tn = t & 15, tm = t >> 4;

  // decode linear block -> (bi, bj), bi<=bj
  int lin = blockIdx.x;
  int bi = (int)(NB + 0.5 - sqrt((NB + 0.5) * (NB + 0.5) - 2.0 * (double)lin));
  if (bi < 0) bi = 0;
  if (bi > NB - 1) bi = NB - 1;
  while (bi + 1 <= NB - 1 && (bi + 1) * NB - ((bi + 1) * bi) / 2 <= lin) ++bi;
  while (bi * NB - (bi * (bi - 1)) / 2 > lin) --bi;
  int bj = bi + (lin - (bi * NB - (bi * (bi - 1)) / 2));

  const size_t m0 = (size_t)bi * 128, n0 = (size_t)bj * 128;

  float cur[2][2][4][4] = {};

  for (int kt = 0; kt < DFEAT; kt += 32) {
#pragma unroll
    for (int u = 0; u < 4; ++u) {
      int f = u * 256 + t;
      int r = f >> 3, c = f & 7;
      int pm = (r & 3) + 4 * ((r >> 2) ^ c);
      float4 va = *(const float4*)(F + (m0 + r) * (size_t)DFEAT + kt + 4 * c);
      As[4 * c + 0][pm] = va.x; As[4 * c + 1][pm] = va.y;
      As[4 * c + 2][pm] = va.z; As[4 * c + 3][pm] = va.w;
      float4 vb = *(const float4*)(F + (n0 + r) * (size_t)DFEAT + kt + 4 * c);
      Bs[4 * c + 0][pm] = vb.x; Bs[4 * c + 1][pm] = vb.y;
      Bs[4 * c + 2][pm] = vb.z; Bs[4 * c + 3][pm] = vb.w;
    }
    __syncthreads();
#pragma unroll 4
    for (int kk = 0; kk < 32; ++kk) {
      const int key = kk >> 2;
      float4 a0 = *(const float4*)&As[kk][4 * (tm ^ key)];
      float4 a1 = *(const float4*)&As[kk][4 * (16 + (tm ^ key))];
      float4 b0 = *(const float4*)&Bs[kk][4 * (tn ^ key)];
      float4 b1 = *(const float4*)&Bs[kk][4 * (16 + (tn ^ key))];
      float av[2][4] = {{a0.x, a0.y, a0.z, a0.w}, {a1.x, a1.y, a1.z, a1.w}};
      float bv[2][4] = {{b0.x, b0.y, b0.z, b0.w}, {b1.x, b1.y, b1.z, b1.w}};
#pragma unroll
      for (int ih = 0; ih < 2; ++ih)
#pragma unroll
        for (int jh = 0; jh < 2; ++jh)
#pragma unroll
          for (int i = 0; i < 4; ++i)
#pragma unroll
            for (int j = 0; j < 4; ++j)
              cur[ih][jh][i][j] = fmaf(av[ih][i], bv[jh][j], cur[ih][jh][i][j]);
    }
    __syncthreads();
  }

  // relu in place
#pragma unroll
  for (int ih = 0; ih < 2; ++ih)
#pragma unroll
    for (int jh = 0; jh < 2; ++jh)
#pragma unroll
      for (int i = 0; i < 4; ++i)
#pragma unroll
        for (int j = 0; j < 4; ++j)
          cur[ih][jh][i][j] = cur[ih][jh][i][j] > 0.f ? cur[ih][jh][i][j] : 0.f;

  // normal tile write (coalesced 256B segments)
#pragma unroll
  for (int ih = 0; ih < 2; ++ih)
#pragma unroll
    for (int i = 0; i < 4; ++i) {
      size_t gm = m0 + 64 * ih + 4 * tm + i;
#pragma unroll
      for (int jh = 0; jh < 2; ++jh) {
        float4 res = {cur[ih][jh][i][0], cur[ih][jh][i][1],
                      cur[ih][jh][i][2], cur[ih][jh][i][3]};
        *(float4*)(C + gm * (size_t)NROW + n0 + 64 * jh + 4 * tn) = res;
      }
    }

  // mirrored tile: LDS transpose (64 rows per jh-chunk), then coalesced stores
  if (bi != bj) {
#pragma unroll
    for (int jh = 0; jh < 2; ++jh) {
      __syncthreads();   // previous chunk reads (or k-loop/As reads) complete
#pragma unroll
      for (int ih = 0; ih < 2; ++ih)
#pragma unroll
        for (int j = 0; j < 4; ++j) {
          int rowl = 4 * tn + j;              // mirror-row within chunk, 0..63
          int slot = 16 * ih + tm;            // float4-slot along mirror row, 0..31
          int phys = slot ^ (rowl >> 2);      // conflict-free swizzle
          Ts[rowl * 32 + phys] =
              make_float4(cur[ih][jh][0][j], cur[ih][jh][1][j],
                          cur[ih][jh][2][j], cur[ih][jh][3][j]);
        }
      __syncthreads();
      {
        int rowr = t >> 2;                    // 0..63
        size_t gn = n0 + 64 * jh + rowr;
#pragma unroll
        for (int q = 0; q < 8; ++q) {
          int s = (t & 3) + 4 * q;            // logical slot: 64B contiguous / 4 lanes
          int phys = s ^ (rowr >> 2);
          float4 v = Ts[rowr * 32 + phys];
          *(float4*)(C + gn * (size_t)NROW + m0 + 4 * s) = v;
        }
      }
    }
  }
}

// ---------------- norm + fn: numpy classic pairwise (UNCHANGED, bit-critical) -----
__global__ __launch_bounds__(256) void norm_fn_kernel(const float* __restrict__ feat,
                                                      float* __restrict__ fn) {
#pragma clang fp contract(off)
  const int row = blockIdx.x * 4 + (threadIdx.x >> 6);
  const int lane = threadIdx.x & 63;
  const float* fr = feat + (size_t)row * DFEAT;
  float r = 0.f;
  if (lane < 32) {
    const float* bp = fr + (lane >> 3) * 128 + (lane & 7);
    float x = bp[0];
    r = x * x;
#pragma unroll
    for (int i = 8; i <= 120; i += 8) {
      float x2 = bp[i];
      float s = x2 * x2;
      r = r + s;
    }
  }
  float v[32];
#pragma unroll
  for (int j = 0; j < 32; ++j) v[j] = __shfl(r, j);
  float Bv[4];
#pragma unroll
  for (int b = 0; b < 4; ++b) {
    const float* p = v + 8 * b;
    Bv[b] = ((p[0] + p[1]) + (p[2] + p[3])) + ((p[4] + p[5]) + (p[6] + p[7]));
  }
  float S = (Bv[0] + Bv[1]) + (Bv[2] + Bv[3]);
  float den = (float)sqrt((double)S) + 1e-8f;
#pragma unroll
  for (int e = 0; e < 8; ++e) {
    int d = e * 64 + lane;
    fn[(size_t)row * DFEAT + d] = fr[d] / den;
  }
}

// ---------------- per-row top-32: exact byte-radix select + fused row-zero -------
// Privatized per-wave histograms; each block zeroes ITS OWN row right after
// staging it to LDS (replaces standalone zero_kernel; lines L2-hot).
__device__ __forceinline__ void radix_scan(const unsigned int (*h4)[256], int* st, int t) {
  if (t < 64) {
    int h0 = (int)(h4[0][4 * t + 0] + h4[1][4 * t + 0] + h4[2][4 * t + 0] + h4[3][4 * t + 0]);
    int h1 = (int)(h4[0][4 * t + 1] + h4[1][4 * t + 1] + h4[2][4 * t + 1] + h4[3][4 * t + 1]);
    int h2 = (int)(h4[0][4 * t + 2] + h4[1][4 * t + 2] + h4[2][4 * t + 2] + h4[3][4 * t + 2]);
    int h3 = (int)(h4[0][4 * t + 3] + h4[1][4 * t + 3] + h4[2][4 * t + 3] + h4[3][4 * t + 3]);
    int S = h0 + h1 + h2 + h3;
#pragma unroll
    for (int off = 1; off < 64; off <<= 1) {
      int o = __shfl_down(S, off);
      if (t + off < 64) S += o;
    }
    int Sn = __shfl_down(S, 1);
    if (t == 63) Sn = 0;
    int needed = st[1];
    if (S >= needed && Sn < needed) {
      int cg = Sn, b;
      if (cg + h3 >= needed) b = 3;
      else if ((cg += h3) + h2 >= needed) b = 2;
      else if ((cg += h2) + h1 >= needed) b = 1;
      else { cg += h1; b = 0; }
      st[0] = (st[0] << 8) | (4 * t + b);
      st[1] = needed - cg;
    }
    if (t == 0 && S < needed) { st[2] = 1; st[1] = needed - S; }
  }
}

__global__ __launch_bounds__(256, 3) void topk_kernel(
    float* __restrict__ sim, float* __restrict__ topv, int* __restrict__ topi)
{
  __shared__ __align__(16) unsigned int svb[NROW];  // 48 KiB: row value bits
  __shared__ unsigned int hist4[4][256];            // per-wave histograms
  __shared__ int st[4];
  __shared__ int smin[4];
  const int row = blockIdx.x, t = threadIdx.x;
  float4* rp = (float4*)(sim + (size_t)row * NROW);
  unsigned int* myh = hist4[t >> 6];

#pragma unroll
  for (int w = 0; w < 4; ++w) hist4[w][t] = 0;
  if (t == 0) { st[0] = 0; st[1] = 32; st[2] = 0; st[3] = 0; }
  __syncthreads();

  const float4 z4 = make_float4(0.f, 0.f, 0.f, 0.f);
#pragma unroll
  for (int it = 0; it < 12; ++it) {
    int q = t + 256 * it;
    float4 v = rp[q];
    unsigned w0 = __float_as_uint(v.x), w1 = __float_as_uint(v.y),
             w2 = __float_as_uint(v.z), w3 = __float_as_uint(v.w);
    uint4 u; u.x = w0; u.y = w1; u.z = w2; u.w = w3;
    *(uint4*)&svb[4 * q] = u;
    rp[q] = z4;                     // fused zero: own row, L2-hot, no cold RFO
    if (w0) atomicAdd(&myh[w0 >> 24], 1u);
    if (w1) atomicAdd(&myh[w1 >> 24], 1u);
    if (w2) atomicAdd(&myh[w2 >> 24], 1u);
    if (w3) atomicAdd(&myh[w3 >> 24], 1u);
  }
  __syncthreads();
  radix_scan(hist4, st, t);
  __syncthreads();

  for (int p = 1; p < 4; ++p) {
    if (st[2]) break;
    unsigned pref = (unsigned)st[0];
    const int sh = 24 - 8 * p;
#pragma unroll
    for (int w = 0; w < 4; ++w) hist4[w][t] = 0;
    __syncthreads();
#pragma unroll
    for (int it = 0; it < 12; ++it) {
      uint4 u = *(const uint4*)&svb[4 * (t + 256 * it)];
      unsigned ws[4] = {u.x, u.y, u.z, u.w};
#pragma unroll
      for (int e = 0; e < 4; ++e)
        if ((ws[e] >> (sh + 8)) == pref)
          atomicAdd(&myh[(ws[e] >> sh) & 255u], 1u);
    }
    __syncthreads();
    radix_scan(hist4, st, t);
    __syncthreads();
  }

  const unsigned T = (unsigned)st[0];
  const int r = st[1];

#pragma unroll
  for (int it = 0; it < 12; ++it) {
    uint4 u = *(const uint4*)&svb[4 * (t + 256 * it)];
    unsigned ws[4] = {u.x, u.y, u.z, u.w};
#pragma unroll
    for (int e = 0; e < 4; ++e)
      if (ws[e] > T) {
        int pos = atomicAdd(&st[3], 1);
        topv[row * 32 + pos] = __uint_as_float(ws[e]);
        topi[row * 32 + pos] = 4 * (t + 256 * it) + e;
      }
  }

  int last = -1;
  const int base = 32 - r;
  for (int rd = 0; rd < r; ++rd) {
    int lm = 0x7fffffff;
#pragma unroll
    for (int it = 0; it < 12; ++it) {
      uint4 u = *(const uint4*)&svb[4 * (t + 256 * it)];
      unsigned ws[4] = {u.x, u.y, u.z, u.w};
#pragma unroll
      for (int e = 0; e < 4; ++e) {
        int j = 4 * (t + 256 * it) + e;
        if (ws[e] == T && j > last && j < lm) lm = j;
      }
    }
#pragma unroll
    for (int off = 32; off >= 1; off >>= 1) {
      int o = __shfl_xor(lm, off);
      if (o < lm) lm = o;
    }
    if ((t & 63) == 0) smin[t >> 6] = lm;
    __syncthreads();
    int g0 = smin[0] < smin[1] ? smin[0] : smin[1];
    int g1 = smin[2] < smin[3] ? smin[2] : smin[3];
    int g = g0 < g1 ? g0 : g1;
    if (t == 0) {
      topv[row * 32 + base + rd] = __uint_as_float(T);
      topi[row * 32 + base + rd] = g;
    }
    last = g;
    __syncthreads();
  }
}

// ---------------- scatter ----------------
__global__ __launch_bounds__(256) void scatter_kernel(
    const float* __restrict__ topv, const int* __restrict__ topi, float* __restrict__ out) {
  int g = blockIdx.x * 256 + threadIdx.x;
  int row = g >> 5;
  float v = 0.5f * topv[g];
  int j = topi[g];
  atomicAdd(out + (size_t)row * NROW + j, v);
  atomicAdd(out + (size_t)j * NROW + row, v);
}

// ---------------- launch ----------------
extern "C" void kernel_launch(void* const* d_in, const int* in_sizes, int n_in,
                              void* d_out, int out_size, void* d_ws, size_t ws_size,
                              hipStream_t stream)
{
  const float* X  = (const float*)d_in[0];
  const float* W1 = (const float*)d_in[1];
  const float* b1 = (const float*)d_in[2];
  const float* W2 = (const float*)d_in[3];
  const float* b2 = (const float*)d_in[4];
  const float* W3 = (const float*)d_in[5];
  const float* b3 = (const float*)d_in[6];
  float* out = (float*)d_out;

  char* ws = (char*)d_ws;
  size_t off = 0;
  auto carve = [&](size_t bytes) {
    char* p = ws + off;
    off += (bytes + 255) & ~(size_t)255;
    return (void*)p;
  };

  float* h1   = (float*)carve(4ull * NROW * HDIM);
  float* h2   = (float*)carve(4ull * NROW * HDIM);
  float* feat = (float*)carve(4ull * NROW * DFEAT);
  float* fn   = (float*)carve(4ull * NROW * DFEAT);
  float* topv = (float*)carve(4ull * NROW * 32);
  int*   topi = (int*)carve(4ull * NROW * 32);

  // MLP (chains bit-identical to round 9: K=512 single, K=1024 -> (512,512))
  gemm128<0, 1><<<dim3(HDIM / 128, NROW / 128), 256, 0, stream>>>(
      X, W1, b1, nullptr, h1, HDIM, DFEAT);
  gemm128<0, 2><<<dim3(HDIM / 128, NROW / 128), 256, 0, stream>>>(
      h1, W2, b2, nullptr, h2, HDIM, HDIM);
  gemm128<1, 2><<<dim3(DFEAT / 128, NROW / 128), 256, 0, stream>>>(
      h2, W3, b3, X, feat, DFEAT, HDIM);

  // norm + fn
  norm_fn_kernel<<<NROW / 4, 256, 0, stream>>>(feat, fn);

  // sim = relu(fn @ fn^T), symmetric: 4656 upper-tri blocks
  gemmsym<<<dim3(NB * (NB + 1) / 2), 256, 0, stream>>>(fn, out);

  // top-32 per row + fused zeroing of each row
  topk_kernel<<<NROW, 256, 0, stream>>>(out, topv, topi);

  // symmetric scatter into the (now zeroed) output
  scatter_kernel<<<(NROW * 32) / 256, 256, 0, stream>>>(topv, topi, out);
}